// Round 1
// baseline (889.399 us; speedup 1.0000x reference)
//
#include <hip/hip_runtime.h>
#include <cstdint>

// Problem: B=131072, D=256, C=1000
// out = [ logits[B,C] fp32 ; weight[C,D] fp32 ]
// logits[b,c] = min(2*dot(xn_b, wn_c) - 2, 0)
//
// Structure: ONE gemm pass over x. Each block owns 128 x-rows:
//   - reads x fp32 once, normalizes in-register (rows already in MFMA A-frag lane layout),
//   - keeps all A fragments in VGPRs for the whole kernel (64 VGPR),
//   - loops over all 16 n-tiles of wn (bf16, pre-swizzled, L2-resident),
//     double-buffered 32 KiB LDS staging via global_load_lds,
//   - swapped-operand MFMA => float4 nontemporal stores (coalesced, no cache pollution).
// HBM traffic: 134 MB x read (once) + 524 MB logits write + ~1 MB wn  ~= floor.

#define B_ROWS 131072
#define D_DIM 256
#define C_DIM 1000
#define C_PAD 1024
#define OUT_LOGITS ((size_t)B_ROWS * (size_t)C_DIM)

#define BM 128                 // x rows per block (4 waves x 32 rows)
#define BN 64                  // wn rows per n-tile
#define NTILES (C_PAD / BN)    // 16

typedef __bf16 bf16x8 __attribute__((ext_vector_type(8)));
typedef float f32x4 __attribute__((ext_vector_type(4)));

typedef __attribute__((address_space(1))) void gbl_void;
typedef __attribute__((address_space(3))) void lds_void;

__device__ __forceinline__ void g2l16(const void* g, void* l) {
    // global -> LDS direct DMA, 16B per lane; LDS dest = wave-uniform base + lane*16
    __builtin_amdgcn_global_load_lds((gbl_void*)(uintptr_t)g,
                                     (lds_void*)(uint32_t)(uintptr_t)l, 16, 0, 0);
}

__device__ __forceinline__ unsigned short f2bf(float f) {
    unsigned int u = __builtin_bit_cast(unsigned int, f);
    u = (u + 0x7fffu + ((u >> 16) & 1u)) >> 16;  // RNE
    return (unsigned short)u;
}

// Normalize weight rows -> bf16 wn[C_PAD][256], stored PRE-SWIZZLED so that a linear
// global_load_lds copy lands in LDS with the XOR bank swizzle already applied:
//   row r (512 B) = 32 chunks of 16 B; chunk c stored at slot (c&~7)|((c&7)^(r&7)).
// Rows >= 1000 zero-padded. Also copies weight -> out tail passthrough.
__global__ void prep_w(const float* __restrict__ w, unsigned short* __restrict__ wn,
                       float* __restrict__ out_tail) {
    const int row = blockIdx.x * 4 + (threadIdx.x >> 6);
    const int lane = threadIdx.x & 63;
    const int c = lane >> 1, h = lane & 1;             // 16B chunk id, half-chunk
    const int slot = (c & ~7) | ((c & 7) ^ (row & 7)); // XOR swizzle
    ushort4* dst = (ushort4*)wn + (size_t)row * 64 + slot * 2 + h;
    if (row < C_DIM) {
        float4 v = ((const float4*)(w + (size_t)row * D_DIM))[lane];
        float s = v.x * v.x + v.y * v.y + v.z * v.z + v.w * v.w;
#pragma unroll
        for (int off = 32; off; off >>= 1) s += __shfl_xor(s, off, 64);
        float inv = 1.0f / fmaxf(sqrtf(s), 1e-12f);
        ushort4 o = { f2bf(v.x * inv), f2bf(v.y * inv), f2bf(v.z * inv), f2bf(v.w * inv) };
        *dst = o;
        ((float4*)(out_tail + (size_t)row * D_DIM))[lane] = v;  // passthrough output
    } else {
        ushort4 z = { 0, 0, 0, 0 };
        *dst = z;
    }
}

// Fused normalize + NT GEMM. Grid = B_ROWS/BM = 1024 blocks, 256 threads (4 waves).
// Wave w owns rows [m0 + w*32, +32). A frags register-resident across all n-tiles.
__global__ __launch_bounds__(256, 2) void gemm_logits(const float* __restrict__ x,
                                                      const unsigned short* __restrict__ wn,
                                                      float* __restrict__ out) {
    __shared__ __align__(16) unsigned short Bs[2][BN * D_DIM];  // 2 x 32 KiB

    const int tid = threadIdx.x;
    const int w = tid >> 6;
    const int lane = tid & 63;
    const int mfrag = lane & 15;
    const int quad = lane >> 4;
    const size_t m0 = (size_t)blockIdx.x * BM;

    // ---- stage B tile 0 into Bs[0]; in flight during the normalize phase ----
    {
        const char* src = (const char*)wn;
        char* dst = (char*)&Bs[0][0];
#pragma unroll
        for (int i = 0; i < 8; i++)
            g2l16(src + (w * 8 + i) * 1024 + lane * 16, dst + (w * 8 + i) * 1024);
    }

    // ---- fused x normalization -> bf16 A fragments in registers ----
    // A-frag layout (16x16x32): row = lane&15, k = quad*8 + [0..8). A row lives on the
    // 4 lanes {l, l^16, l^32, l^48} -> rowsum via two shfl_xor.
    bf16x8 af[2][8];  // [row-group of 16][k-chunk of 32]  = 64 VGPR
#pragma unroll
    for (int r2 = 0; r2 < 2; r2++) {
        const float* xr = x + (m0 + (size_t)(w * 32 + r2 * 16 + mfrag)) * D_DIM + quad * 8;
        f32x4 v0[8], v1[8];
        float s = 0.f;
#pragma unroll
        for (int kc = 0; kc < 8; kc++) {
            v0[kc] = *(const f32x4*)(xr + kc * 32);
            v1[kc] = *(const f32x4*)(xr + kc * 32 + 4);
#pragma unroll
            for (int e = 0; e < 4; e++) s += v0[kc][e] * v0[kc][e] + v1[kc][e] * v1[kc][e];
        }
        s += __shfl_xor(s, 16, 64);
        s += __shfl_xor(s, 32, 64);
        const float inv = 1.0f / fmaxf(sqrtf(s), 1e-12f);
#pragma unroll
        for (int kc = 0; kc < 8; kc++) {
            bf16x8 a;
#pragma unroll
            for (int e = 0; e < 4; e++) {
                a[e]     = __builtin_bit_cast(__bf16, f2bf(v0[kc][e] * inv));
                a[e + 4] = __builtin_bit_cast(__bf16, f2bf(v1[kc][e] * inv));
            }
            af[r2][kc] = a;
        }
    }

    // Per-wave output row pointers (m fixed across the whole n loop -> no 64-bit mul in loop)
    float* prow0 = out + (m0 + (size_t)(w * 32 + mfrag)) * C_DIM;
    float* prow1 = prow0 + (size_t)16 * C_DIM;

#pragma unroll 1
    for (int t = 0; t < NTILES; t++) {
        __syncthreads();  // drains vmcnt: Bs[t&1] staged; prior reads of other buf done

        if (t + 1 < NTILES) {  // prefetch next tile into the other buffer
            const char* src = (const char*)wn + (size_t)(t + 1) * (BN * D_DIM * 2);
            char* dst = (char*)&Bs[(t + 1) & 1][0];
#pragma unroll
            for (int i = 0; i < 8; i++)
                g2l16(src + (w * 8 + i) * 1024 + lane * 16, dst + (w * 8 + i) * 1024);
        }

        f32x4 acc[2][4];
#pragma unroll
        for (int r2 = 0; r2 < 2; r2++)
#pragma unroll
            for (int g = 0; g < 4; g++) acc[r2][g] = { 0.f, 0.f, 0.f, 0.f };

        const char* bsb = (const char*)&Bs[t & 1][0];
#pragma unroll
        for (int kc = 0; kc < 8; kc++) {
            bf16x8 bq[4];
#pragma unroll
            for (int g = 0; g < 4; g++) {
                const int r = g * 16 + mfrag;                    // wn row within tile
                const int c = kc * 4 + quad;                     // 16B k-chunk
                const int slot = (c & ~7) | ((c & 7) ^ (r & 7)); // matches prep_w swizzle
                bq[g] = *(const bf16x8*)(bsb + r * 512 + slot * 16);
            }
#pragma unroll
            for (int g = 0; g < 4; g++) {
                // swapped operands: D col(lane&15) = x-row, D regs = 4 consecutive n
                acc[0][g] = __builtin_amdgcn_mfma_f32_16x16x32_bf16(bq[g], af[0][kc], acc[0][g], 0, 0, 0);
                acc[1][g] = __builtin_amdgcn_mfma_f32_16x16x32_bf16(bq[g], af[1][kc], acc[1][g], 0, 0, 0);
            }
        }

        // Epilogue: lane holds 4 consecutive n for its m-row -> float4 NT stores.
        // n is a multiple of 4 and C_DIM % 4 == 0 -> predicate & alignment are clean.
#pragma unroll
        for (int g = 0; g < 4; g++) {
            const int n = t * BN + g * 16 + quad * 4;
            if (n < C_DIM) {
                f32x4 o0, o1;
#pragma unroll
                for (int e = 0; e < 4; e++) {
                    o0[e] = fminf(2.0f * acc[0][g][e] - 2.0f, 0.0f);
                    o1[e] = fminf(2.0f * acc[1][g][e] - 2.0f, 0.0f);
                }
                __builtin_nontemporal_store(o0, (f32x4*)(prow0 + n));
                __builtin_nontemporal_store(o1, (f32x4*)(prow1 + n));
            }
        }
    }
}

extern "C" void kernel_launch(void* const* d_in, const int* in_sizes, int n_in,
                              void* d_out, int out_size, void* d_ws, size_t ws_size,
                              hipStream_t stream) {
    const float* x = (const float*)d_in[0];
    const float* w = (const float*)d_in[1];
    float* out = (float*)d_out;

    unsigned short* wn = (unsigned short*)d_ws;  // 512 KiB, pre-swizzled bf16

    prep_w<<<C_PAD / 4, 256, 0, stream>>>(w, wn, out + OUT_LOGITS);
    gemm_logits<<<B_ROWS / BM, 256, 0, stream>>>(x, wn, out);
}

// Round 2
// 674.343 us; speedup vs baseline: 1.3189x; 1.3189x over previous
//
#include <hip/hip_runtime.h>
#include <cstdint>

// Problem: B=131072, D=256, C=1000
// out = [ logits[B,C] fp32 ; weight[C,D] fp32 ]
// logits[b,c] = min(2*dot(xn_b, wn_c) - 2, 0)
//
// Structure: ONE gemm pass over x. Each block owns 128 x-rows:
//   - reads x fp32 once, normalizes in-register (rows already in MFMA A-frag lane layout),
//   - keeps all A fragments in VGPRs for the whole kernel (64 VGPR),
//   - loops over all 16 n-tiles of wn (bf16, pre-swizzled, L2-resident),
//     double-buffered 32 KiB LDS staging via global_load_lds,
//   - swapped-operand MFMA => float4 CACHED stores (L2 merges the 64-B row
//     segments into full lines; NT stores measured 1.64 TB/s + 37% write
//     inflation in round 1 — do NOT bypass L2 here).
// HBM traffic: 134 MB x read (once) + 524 MB logits write + ~1 MB wn  ~= floor.

#define B_ROWS 131072
#define D_DIM 256
#define C_DIM 1000
#define C_PAD 1024
#define OUT_LOGITS ((size_t)B_ROWS * (size_t)C_DIM)

#define BM 128                 // x rows per block (4 waves x 32 rows)
#define BN 64                  // wn rows per n-tile
#define NTILES (C_PAD / BN)    // 16

typedef __bf16 bf16x8 __attribute__((ext_vector_type(8)));
typedef float f32x4 __attribute__((ext_vector_type(4)));

typedef __attribute__((address_space(1))) void gbl_void;
typedef __attribute__((address_space(3))) void lds_void;

__device__ __forceinline__ void g2l16(const void* g, void* l) {
    // global -> LDS direct DMA, 16B per lane; LDS dest = wave-uniform base + lane*16
    __builtin_amdgcn_global_load_lds((gbl_void*)(uintptr_t)g,
                                     (lds_void*)(uint32_t)(uintptr_t)l, 16, 0, 0);
}

__device__ __forceinline__ unsigned short f2bf(float f) {
    unsigned int u = __builtin_bit_cast(unsigned int, f);
    u = (u + 0x7fffu + ((u >> 16) & 1u)) >> 16;  // RNE
    return (unsigned short)u;
}

// Normalize weight rows -> bf16 wn[C_PAD][256], stored PRE-SWIZZLED so that a linear
// global_load_lds copy lands in LDS with the XOR bank swizzle already applied:
//   row r (512 B) = 32 chunks of 16 B; chunk c stored at slot (c&~7)|((c&7)^(r&7)).
// Rows >= 1000 zero-padded. Also copies weight -> out tail passthrough.
__global__ void prep_w(const float* __restrict__ w, unsigned short* __restrict__ wn,
                       float* __restrict__ out_tail) {
    const int row = blockIdx.x * 4 + (threadIdx.x >> 6);
    const int lane = threadIdx.x & 63;
    const int c = lane >> 1, h = lane & 1;             // 16B chunk id, half-chunk
    const int slot = (c & ~7) | ((c & 7) ^ (row & 7)); // XOR swizzle
    ushort4* dst = (ushort4*)wn + (size_t)row * 64 + slot * 2 + h;
    if (row < C_DIM) {
        float4 v = ((const float4*)(w + (size_t)row * D_DIM))[lane];
        float s = v.x * v.x + v.y * v.y + v.z * v.z + v.w * v.w;
#pragma unroll
        for (int off = 32; off; off >>= 1) s += __shfl_xor(s, off, 64);
        float inv = 1.0f / fmaxf(sqrtf(s), 1e-12f);
        ushort4 o = { f2bf(v.x * inv), f2bf(v.y * inv), f2bf(v.z * inv), f2bf(v.w * inv) };
        *dst = o;
        ((float4*)(out_tail + (size_t)row * D_DIM))[lane] = v;  // passthrough output
    } else {
        ushort4 z = { 0, 0, 0, 0 };
        *dst = z;
    }
}

// Fused normalize + NT GEMM. Grid = B_ROWS/BM = 1024 blocks, 256 threads (4 waves).
// Wave w owns rows [m0 + w*32, +32). A frags register-resident across all n-tiles.
__global__ __launch_bounds__(256, 2) void gemm_logits(const float* __restrict__ x,
                                                      const unsigned short* __restrict__ wn,
                                                      float* __restrict__ out) {
    __shared__ __align__(16) unsigned short Bs[2][BN * D_DIM];  // 2 x 32 KiB

    const int tid = threadIdx.x;
    const int w = tid >> 6;
    const int lane = tid & 63;
    const int mfrag = lane & 15;
    const int quad = lane >> 4;
    const size_t m0 = (size_t)blockIdx.x * BM;

    // ---- stage B tile 0 into Bs[0]; in flight during the normalize phase ----
    {
        const char* src = (const char*)wn;
        char* dst = (char*)&Bs[0][0];
#pragma unroll
        for (int i = 0; i < 8; i++)
            g2l16(src + (w * 8 + i) * 1024 + lane * 16, dst + (w * 8 + i) * 1024);
    }

    // ---- fused x normalization -> bf16 A fragments in registers ----
    // A-frag layout (16x16x32): row = lane&15, k = quad*8 + [0..8). A row lives on the
    // 4 lanes {l, l^16, l^32, l^48} -> rowsum via two shfl_xor.
    bf16x8 af[2][8];  // [row-group of 16][k-chunk of 32]  = 64 VGPR
#pragma unroll
    for (int r2 = 0; r2 < 2; r2++) {
        const float* xr = x + (m0 + (size_t)(w * 32 + r2 * 16 + mfrag)) * D_DIM + quad * 8;
        f32x4 v0[8], v1[8];
        float s = 0.f;
#pragma unroll
        for (int kc = 0; kc < 8; kc++) {
            v0[kc] = *(const f32x4*)(xr + kc * 32);
            v1[kc] = *(const f32x4*)(xr + kc * 32 + 4);
#pragma unroll
            for (int e = 0; e < 4; e++) s += v0[kc][e] * v0[kc][e] + v1[kc][e] * v1[kc][e];
        }
        s += __shfl_xor(s, 16, 64);
        s += __shfl_xor(s, 32, 64);
        const float inv = 1.0f / fmaxf(sqrtf(s), 1e-12f);
#pragma unroll
        for (int kc = 0; kc < 8; kc++) {
            bf16x8 a;
#pragma unroll
            for (int e = 0; e < 4; e++) {
                a[e]     = __builtin_bit_cast(__bf16, f2bf(v0[kc][e] * inv));
                a[e + 4] = __builtin_bit_cast(__bf16, f2bf(v1[kc][e] * inv));
            }
            af[r2][kc] = a;
        }
    }

    // Per-wave output row pointers (m fixed across the whole n loop -> no 64-bit mul in loop)
    float* prow0 = out + (m0 + (size_t)(w * 32 + mfrag)) * C_DIM;
    float* prow1 = prow0 + (size_t)16 * C_DIM;

#pragma unroll 1
    for (int t = 0; t < NTILES; t++) {
        __syncthreads();  // drains vmcnt: Bs[t&1] staged; prior reads of other buf done

        if (t + 1 < NTILES) {  // prefetch next tile into the other buffer
            const char* src = (const char*)wn + (size_t)(t + 1) * (BN * D_DIM * 2);
            char* dst = (char*)&Bs[(t + 1) & 1][0];
#pragma unroll
            for (int i = 0; i < 8; i++)
                g2l16(src + (w * 8 + i) * 1024 + lane * 16, dst + (w * 8 + i) * 1024);
        }

        f32x4 acc[2][4];
#pragma unroll
        for (int r2 = 0; r2 < 2; r2++)
#pragma unroll
            for (int g = 0; g < 4; g++) acc[r2][g] = { 0.f, 0.f, 0.f, 0.f };

        const char* bsb = (const char*)&Bs[t & 1][0];
#pragma unroll
        for (int kc = 0; kc < 8; kc++) {
            bf16x8 bq[4];
#pragma unroll
            for (int g = 0; g < 4; g++) {
                const int r = g * 16 + mfrag;                    // wn row within tile
                const int c = kc * 4 + quad;                     // 16B k-chunk
                const int slot = (c & ~7) | ((c & 7) ^ (r & 7)); // matches prep_w swizzle
                bq[g] = *(const bf16x8*)(bsb + r * 512 + slot * 16);
            }
#pragma unroll
            for (int g = 0; g < 4; g++) {
                // swapped operands: D col(lane&15) = x-row, D regs = 4 consecutive n
                acc[0][g] = __builtin_amdgcn_mfma_f32_16x16x32_bf16(bq[g], af[0][kc], acc[0][g], 0, 0, 0);
                acc[1][g] = __builtin_amdgcn_mfma_f32_16x16x32_bf16(bq[g], af[1][kc], acc[1][g], 0, 0, 0);
            }
        }

        // Epilogue: lane holds 4 consecutive n for its m-row -> float4 CACHED stores.
        // L2 merges the 64-B per-row segments into full lines; consecutive tiles
        // complete the phase-32 boundary lines while still resident.
#pragma unroll
        for (int g = 0; g < 4; g++) {
            const int n = t * BN + g * 16 + quad * 4;
            if (n < C_DIM) {
                f32x4 o0, o1;
#pragma unroll
                for (int e = 0; e < 4; e++) {
                    o0[e] = fminf(2.0f * acc[0][g][e] - 2.0f, 0.0f);
                    o1[e] = fminf(2.0f * acc[1][g][e] - 2.0f, 0.0f);
                }
                *(f32x4*)(prow0 + n) = o0;
                *(f32x4*)(prow1 + n) = o1;
            }
        }
    }
}

extern "C" void kernel_launch(void* const* d_in, const int* in_sizes, int n_in,
                              void* d_out, int out_size, void* d_ws, size_t ws_size,
                              hipStream_t stream) {
    const float* x = (const float*)d_in[0];
    const float* w = (const float*)d_in[1];
    float* out = (float*)d_out;

    unsigned short* wn = (unsigned short*)d_ws;  // 512 KiB, pre-swizzled bf16

    prep_w<<<C_PAD / 4, 256, 0, stream>>>(w, wn, out + OUT_LOGITS);
    gemm_logits<<<B_ROWS / BM, 256, 0, stream>>>(x, wn, out);
}